// Round 6
// baseline (309.931 us; speedup 1.0000x reference)
//
#include <hip/hip_runtime.h>

#define BT    8192
#define MS    8                // samples per fused block
#define P_STR 264              // halves per pixel row in Xs (256 + 8 pad)
#define S_STR 4232             // halves per sample in Xs (16*264 + 8 pad)
// Xs total: 8*4232 = 33856 halves = 67712 B; Pl after it: 8*264*2 = 4224 B

typedef _Float16 half8  __attribute__((ext_vector_type(8)));
typedef _Float16 half4v __attribute__((ext_vector_type(4)));
typedef float    floatx4  __attribute__((ext_vector_type(4)));
typedef float    floatx16 __attribute__((ext_vector_type(16)));

// ---------------- K0: all weight pre-transforms in one launch -------------
// blocks 0..255   : conv weight -> W3[step][256n][32c]
// blocks 256..327 : KAN weights -> Wk3
// blocks 328..335 : fc1 weights -> Wf3
__global__ __launch_bounds__(256) void prep_kernel(
    const float* __restrict__ weight, const float* __restrict__ base_w,
    const float* __restrict__ spline_w, const float* __restrict__ scaler,
    const float* __restrict__ fc1_w,
    _Float16* __restrict__ W3, _Float16* __restrict__ Wk3,
    _Float16* __restrict__ Wf3)
{
    const int bb = blockIdx.x;
    const int tid = threadIdx.x;
    if (bb < 256) {
        const int n = bb;              // 0..255  (= kbank*64 + o)
        const int c = tid;             // 0..255
        const float* src = weight + ((size_t)n * 256 + c) * 9;
        const int cc = c >> 5, ci = c & 31;
        #pragma unroll
        for (int ij = 0; ij < 9; ++ij) {
            W3[((size_t)(cc * 9 + ij) * 256 + n) * 32 + ci] = (_Float16)src[ij];
        }
    } else if (bb < 328) {
        const int st = bb - 256;       // 0..71
        #pragma unroll
        for (int u = 0; u < 8; ++u) {
            const int idx = u * 256 + tid;       // n*32 + kk
            const int n = idx >> 5, kk = idx & 31;
            const int k = st * 32 + kk;
            float v;
            if (k < 256) {
                v = base_w[n * 256 + k];
            } else {
                const int r = k - 256;
                const int i = r >> 3, g = r & 7;
                v = spline_w[((size_t)n * 256 + i) * 8 + g] * scaler[n * 256 + i];
            }
            Wk3[(size_t)st * 2048 + idx] = (_Float16)v;
        }
    } else {
        const int st2 = bb - 328;      // 0..7
        #pragma unroll
        for (int u = 0; u < 8; ++u) {
            const int idx = u * 256 + tid;
            const int n = idx >> 5, kk = idx & 31;
            Wf3[(size_t)st2 * 2048 + idx] = (_Float16)fc1_w[n * 256 + st2 * 32 + kk];
        }
    }
}

// Uniform cubic B-spline, closed form: only 4 of 8 bases nonzero.
// grid g[t] = (t-3)*0.4 - 1  ->  interval idx = floor((x+2.2)/0.4)
__device__ __forceinline__ void bases8c(float xv, _Float16* dst) {
    const float t = (xv + 2.2f) * 2.5f;
    const float ft = floorf(t);
    const int idx = (int)ft;
    const float u = t - ft, v = 1.f - u;
    const float u2 = u * u, v2 = v * v;
    const float c3 = u2 * u * (1.f / 6.f);                    // B_idx
    const float c2 = (1.f / 6.f) + 0.5f * (u + u2 - u2 * u);  // B_{idx-1}
    const float c1 = (1.f / 6.f) + 0.5f * (v + v2 - v2 * v);  // B_{idx-2}
    const float c0 = v2 * v * (1.f / 6.f);                    // B_{idx-3}
    half8 hb;
    #pragma unroll
    for (int tt = 0; tt < 8; ++tt) {
        const int d = idx - tt;
        float b = 0.f;
        b = (d == 0) ? c3 : b;
        b = (d == 1) ? c2 : b;
        b = (d == 2) ? c1 : b;
        b = (d == 3) ? c0 : b;
        hb[tt] = (_Float16)b;
    }
    *(half8*)dst = hb;
}

// ---------------- Fused: attn + dyn-conv (MFMA) + KAN (MFMA) -> out -------
// MS=8, 256 threads = 4 waves. ALL of x staged once in LDS ([s][pix][ch]
// f16, 67.7 KB), then a 72-tap conv k-loop with ZERO barriers: waves
// desync freely, 3-deep B (W3, L2-resident) register prefetch.
// Conv: wave wv owns kernel-bank wv (4 o-tiles), both row-tiles.
// Epilogue (proven in R5): unweighted f32 partials (one per kbank) into
// the 16-B bases slots, then one pass applies attn + bias + silu + bases.
__global__ __launch_bounds__(256, 2) void fused_kernel(
    const float* __restrict__ x, const _Float16* __restrict__ W3,
    const _Float16* __restrict__ Wk3, const _Float16* __restrict__ Wf3,
    const float* __restrict__ bias, const float* __restrict__ fc1_b,
    const float* __restrict__ fc2_w, const float* __restrict__ fc2_b,
    float* __restrict__ out)
{
    // Overlay: phase A = Xs [0,67712) + Pl [67712,71936)
    //          phase B = Act (8*2312 fp16 = 36992 B) over the Xs region
    __shared__ __align__(16) char smem[71936];
    __shared__ float hid_lds[MS * 68];
    __shared__ float attn_s[MS][4];

    _Float16* Xs  = (_Float16*)smem;
    _Float16* Pl  = (_Float16*)(smem + 67712);
    _Float16* Act = (_Float16*)smem;

    const int tid = threadIdx.x;
    const int wv = tid >> 6, lane = tid & 63;
    const int nl = lane & 15, q = lane >> 4;
    const int b0i = blockIdx.x * MS;

    // ---- stage ALL of x: thread = (sample s_, 4-channel group c4) ----
    const int s_ = tid >> 5, c4 = tid & 31;
    #pragma unroll
    for (int pass = 0; pass < 2; ++pass) {
        const int cbase = pass * 128 + c4 * 4;
        const float* xg = x + ((size_t)(b0i + s_) * 256 + cbase) * 16;
        const floatx16 r0 = *(const floatx16*)(xg);
        const floatx16 r1 = *(const floatx16*)(xg + 16);
        const floatx16 r2 = *(const floatx16*)(xg + 32);
        const floatx16 r3 = *(const floatx16*)(xg + 48);
        _Float16* xd = &Xs[s_ * S_STR + cbase];
        float s0 = 0.f, s1 = 0.f, s2 = 0.f, s3 = 0.f;
        #pragma unroll
        for (int p = 0; p < 16; ++p) {
            half4v w;
            w[0] = (_Float16)r0[p]; w[1] = (_Float16)r1[p];
            w[2] = (_Float16)r2[p]; w[3] = (_Float16)r3[p];
            *(half4v*)&xd[p * P_STR] = w;
            s0 += r0[p]; s1 += r1[p]; s2 += r2[p]; s3 += r3[p];
        }
        half4v pw;
        pw[0] = (_Float16)(s0 * 0.0625f); pw[1] = (_Float16)(s1 * 0.0625f);
        pw[2] = (_Float16)(s2 * 0.0625f); pw[3] = (_Float16)(s3 * 0.0625f);
        *(half4v*)&Pl[s_ * P_STR + cbase] = pw;
    }

    // conv A-fragment base: row nl = (sample nl>>2, out-pixel nl&3)
    const int posr = nl & 3;
    const int pixb = (posr >> 1) * 4 + (posr & 1);
    const int aLane = (nl >> 2) * S_STR + pixb * P_STR + q * 8;
    // B-fragment lane offset for kbank wv; o-tile t adds t*512
    const int lbW = ((wv * 4) * 16 + nl) * 32 + q * 8;

    floatx4 acc[2][4];                 // [row-tile][o-tile]  (kbank = wv)
    #pragma unroll
    for (int rt = 0; rt < 2; ++rt)
        #pragma unroll
        for (int t = 0; t < 4; ++t)
            acc[rt][t] = floatx4{0.f, 0.f, 0.f, 0.f};

    // B prologue: steps 0,1,2 (3-deep rolling pipeline over all 72 steps)
    const _Float16* wl = W3 + lbW;
    half8 b0[4], b1[4], b2[4];
    #pragma unroll
    for (int t = 0; t < 4; ++t) b0[t] = *(const half8*)(wl + t * 512);
    #pragma unroll
    for (int t = 0; t < 4; ++t) b1[t] = *(const half8*)(wl + 8192 + t * 512);
    #pragma unroll
    for (int t = 0; t < 4; ++t) b2[t] = *(const half8*)(wl + 16384 + t * 512);

    __syncthreads();   // x fully staged; NO further barriers in the k-loop

    const _Float16* xbs = Xs + aLane;
    #pragma unroll 1
    for (int cc = 0; cc < 8; ++cc) {
        const _Float16* xb = xbs + cc * 32;
        const _Float16* wst = wl + (size_t)cc * 9 * 8192;
        const int p0tab[9] = {0, 1, 2, 4, 5, 6, 8, 9, 10};
        #pragma unroll
        for (int ij = 0; ij < 9; ++ij) {
            // 3-deep rolling B prefetch (contiguous across chunk bounds)
            const _Float16* wnx = (cc * 9 + ij + 3 < 72)
                                ? (wst + (size_t)(ij + 3) * 8192)
                                : wl;          // dummy (valid) at the tail
            half8 b3[4];
            #pragma unroll
            for (int t = 0; t < 4; ++t)
                b3[t] = *(const half8*)(wnx + t * 512);

            const int po = p0tab[ij] * P_STR;
            const half8 aF0 = *(const half8*)&xb[po];
            const half8 aF1 = *(const half8*)&xb[po + 4 * S_STR];
            #pragma unroll
            for (int t = 0; t < 4; ++t)
                acc[0][t] = __builtin_amdgcn_mfma_f32_16x16x32_f16(aF0, b0[t], acc[0][t], 0, 0, 0);
            #pragma unroll
            for (int t = 0; t < 4; ++t)
                acc[1][t] = __builtin_amdgcn_mfma_f32_16x16x32_f16(aF1, b0[t], acc[1][t], 0, 0, 0);
            #pragma unroll
            for (int t = 0; t < 4; ++t) { b0[t] = b1[t]; b1[t] = b2[t]; b2[t] = b3[t]; }
        }
    }
    __syncthreads();   // conv accs done everywhere; Xs still holds Pl region

    // ---- fc1 via MFMA: wave wv = h-tile wv; 8 real sample rows ----
    {
        floatx4 a1 = floatx4{0.f, 0.f, 0.f, 0.f};
        const _Float16* wfb = Wf3 + ((wv * 16 + nl) * 32 + q * 8);
        const _Float16* pb = &Pl[(nl & 7) * P_STR + q * 8];
        #pragma unroll
        for (int st = 0; st < 8; ++st) {
            const half8 aF = *(const half8*)(pb + st * 32);
            const half8 bF = *(const half8*)(wfb + st * 2048);
            a1 = __builtin_amdgcn_mfma_f32_16x16x32_f16(aF, bF, a1, 0, 0, 0);
        }
        if (q < 2) {
            const int h = wv * 16 + nl;
            const float fb = fc1_b[h];
            #pragma unroll
            for (int reg = 0; reg < 4; ++reg)
                hid_lds[(q * 4 + reg) * 68 + h] = fmaxf(a1[reg] + fb, 0.f);
        }
    }
    __syncthreads();

    // ---- fc2 + softmax (wave 0, 32 lanes) in parallel with
    //      unweighted partial writes (all waves) ----
    if (wv == 0 && lane < 32) {
        const int s = lane >> 2, kb = lane & 3;
        float l = fc2_b[kb];
        #pragma unroll 8
        for (int h = 0; h < 64; ++h) l += hid_lds[s * 68 + h] * fc2_w[kb * 64 + h];
        float m = fmaxf(l, __shfl_xor(l, 1));
        m = fmaxf(m, __shfl_xor(m, 2));
        const float e = __expf((l - m) * (1.0f / 34.0f));
        float sm = e + __shfl_xor(e, 1);
        sm += __shfl_xor(sm, 2);
        attn_s[s][kb] = e / sm;
    }
    // partial writes: Xs dead; Act bases slot [16B] <- fp32 x 4 kbanks
    #pragma unroll
    for (int rt = 0; rt < 2; ++rt) {
        const int s = rt * 4 + q;
        #pragma unroll
        for (int t = 0; t < 4; ++t) {
            #pragma unroll
            for (int e = 0; e < 4; ++e) {
                const int f = (t * 16 + nl) * 4 + e;
                float* fp = (float*)&Act[s * 2312 + 256 + f * 8];
                fp[wv] = acc[rt][t][e];
            }
        }
    }
    __syncthreads();   // attn + all 4 partials ready

    // ---- epilogue: wave wv handles samples {2wv, 2wv+1}; attn-combine +
    //      bias + silu + bases, all in place ----
    {
        const int sl = lane >> 5, fl = lane & 31;
        const int s = wv * 2 + sl;
        const float a0 = attn_s[s][0], a1 = attn_s[s][1],
                    a2 = attn_s[s][2], a3 = attn_s[s][3];
        const int o0 = fl * 2, f0 = fl * 8;
        const float badd0 = a0 * bias[o0] + a1 * bias[64 + o0]
                          + a2 * bias[128 + o0] + a3 * bias[192 + o0];
        const float badd1 = a0 * bias[o0 + 1] + a1 * bias[64 + o0 + 1]
                          + a2 * bias[128 + o0 + 1] + a3 * bias[192 + o0 + 1];
        half8 sv;
        #pragma unroll
        for (int u = 0; u < 8; ++u) {
            float* fp = (float*)&Act[s * 2312 + 256 + (f0 + u) * 8];
            const floatx4 P = *(const floatx4*)fp;
            const float fv = a0 * P[0] + a1 * P[1] + a2 * P[2] + a3 * P[3]
                           + ((u < 4) ? badd0 : badd1);
            const float ex = __expf(-fv);
            sv[u] = (_Float16)(fv * __builtin_amdgcn_rcpf(1.f + ex));
            bases8c(fv, (_Float16*)fp);
        }
        *(half8*)&Act[s * 2312 + o0 * 4] = sv;   // 8 halves = o0,o0+1 silu
    }
    __syncthreads();

    // ---- KAN GEMM: wave wv = o-tile wv, full K (72 steps), 8 rows ----
    {
        floatx4 a2 = floatx4{0.f, 0.f, 0.f, 0.f};
        const _Float16* wkb = Wk3 + ((size_t)(wv * 16 + nl) * 32 + q * 8);
        const _Float16* ab = &Act[(nl & 7) * 2312 + q * 8];
        half8 kb0 = *(const half8*)(wkb);
        half8 kb1 = *(const half8*)(wkb + 2048);
        #pragma unroll 4
        for (int i = 0; i < 72; ++i) {
            half8 kb2;
            if (i < 70) kb2 = *(const half8*)(wkb + (size_t)(i + 2) * 2048);
            const half8 aF = *(const half8*)(ab + i * 32);
            a2 = __builtin_amdgcn_mfma_f32_16x16x32_f16(aF, kb0, a2, 0, 0, 0);
            kb0 = kb1; kb1 = kb2;
        }
        if (q < 2) {
            #pragma unroll
            for (int reg = 0; reg < 4; ++reg)
                out[(size_t)(b0i + q * 4 + reg) * 64 + wv * 16 + nl] = a2[reg];
        }
    }
}

extern "C" void kernel_launch(void* const* d_in, const int* in_sizes, int n_in,
                              void* d_out, int out_size, void* d_ws, size_t ws_size,
                              hipStream_t stream) {
    const float* x          = (const float*)d_in[0];
    const float* weight     = (const float*)d_in[1];
    const float* bias       = (const float*)d_in[2];
    const float* fc1_w      = (const float*)d_in[3];
    const float* fc1_b      = (const float*)d_in[4];
    const float* fc2_w      = (const float*)d_in[5];
    const float* fc2_b      = (const float*)d_in[6];
    const float* kan_base_w = (const float*)d_in[7];
    const float* kan_spline = (const float*)d_in[8];
    const float* kan_scaler = (const float*)d_in[9];
    float* out = (float*)d_out;

    // ws: W3 (72*8192 halves) | Wk3 (72*2048) | Wf3 (8*2048)
    _Float16* W3  = (_Float16*)d_ws;
    _Float16* Wk3 = W3 + (size_t)72 * 8192;
    _Float16* Wf3 = Wk3 + (size_t)72 * 2048;

    prep_kernel<<<336, 256, 0, stream>>>(weight, kan_base_w, kan_spline,
                                         kan_scaler, fc1_w, W3, Wk3, Wf3);
    fused_kernel<<<BT / MS, 256, 0, stream>>>(x, W3, Wk3, Wf3, bias, fc1_b,
                                              fc2_w, fc2_b, out);
}

// Round 8
// 247.768 us; speedup vs baseline: 1.2509x; 1.2509x over previous
//
#include <hip/hip_runtime.h>

#define BT   8192
#define MS   16               // samples per fused block
#define XBUF (MS * 656)       // halves per Xs buffer

typedef _Float16 half8  __attribute__((ext_vector_type(8)));
typedef _Float16 half4v __attribute__((ext_vector_type(4)));
typedef float    floatx2  __attribute__((ext_vector_type(2)));
typedef float    floatx4  __attribute__((ext_vector_type(4)));

// ---------------- K0: all weight pre-transforms in one launch -------------
// blocks 0..255   : conv weight -> W3[step][256n][32c]
// blocks 256..327 : KAN weights -> Wk3
// blocks 328..335 : fc1 weights -> Wf3
__global__ __launch_bounds__(256) void prep_kernel(
    const float* __restrict__ weight, const float* __restrict__ base_w,
    const float* __restrict__ spline_w, const float* __restrict__ scaler,
    const float* __restrict__ fc1_w,
    _Float16* __restrict__ W3, _Float16* __restrict__ Wk3,
    _Float16* __restrict__ Wf3)
{
    const int bb = blockIdx.x;
    const int tid = threadIdx.x;
    if (bb < 256) {
        const int n = bb;              // 0..255  (= kbank*64 + o)
        const int c = tid;             // 0..255
        const float* src = weight + ((size_t)n * 256 + c) * 9;
        const int cc = c >> 5, ci = c & 31;
        #pragma unroll
        for (int ij = 0; ij < 9; ++ij) {
            W3[((size_t)(cc * 9 + ij) * 256 + n) * 32 + ci] = (_Float16)src[ij];
        }
    } else if (bb < 328) {
        const int st = bb - 256;       // 0..71
        #pragma unroll
        for (int u = 0; u < 8; ++u) {
            const int idx = u * 256 + tid;       // n*32 + kk
            const int n = idx >> 5, kk = idx & 31;
            const int k = st * 32 + kk;
            float v;
            if (k < 256) {
                v = base_w[n * 256 + k];
            } else {
                const int r = k - 256;
                const int i = r >> 3, g = r & 7;
                v = spline_w[((size_t)n * 256 + i) * 8 + g] * scaler[n * 256 + i];
            }
            Wk3[(size_t)st * 2048 + idx] = (_Float16)v;
        }
    } else {
        const int st2 = bb - 328;      // 0..7
        #pragma unroll
        for (int u = 0; u < 8; ++u) {
            const int idx = u * 256 + tid;
            const int n = idx >> 5, kk = idx & 31;
            Wf3[(size_t)st2 * 2048 + idx] = (_Float16)fc1_w[n * 256 + st2 * 32 + kk];
        }
    }
}

// Uniform cubic B-spline, closed form: only 4 of 8 bases nonzero.
// grid g[t] = (t-3)*0.4 - 1  ->  interval idx = floor((x+2.2)/0.4)
__device__ __forceinline__ void bases8c(float xv, _Float16* dst) {
    const float t = (xv + 2.2f) * 2.5f;
    const float ft = floorf(t);
    const int idx = (int)ft;
    const float u = t - ft, v = 1.f - u;
    const float u2 = u * u, v2 = v * v;
    const float c3 = u2 * u * (1.f / 6.f);                    // B_idx
    const float c2 = (1.f / 6.f) + 0.5f * (u + u2 - u2 * u);  // B_{idx-1}
    const float c1 = (1.f / 6.f) + 0.5f * (v + v2 - v2 * v);  // B_{idx-2}
    const float c0 = v2 * v * (1.f / 6.f);                    // B_{idx-3}
    half8 hb;
    #pragma unroll
    for (int tt = 0; tt < 8; ++tt) {
        const int d = idx - tt;
        float b = 0.f;
        b = (d == 0) ? c3 : b;
        b = (d == 1) ? c2 : b;
        b = (d == 2) ? c1 : b;
        b = (d == 3) ? c0 : b;
        hb[tt] = (_Float16)b;
    }
    *(half8*)dst = hb;
}

// ---------------- Fused: attn + dyn-conv (MFMA) + KAN (MFMA) -> out -------
// 512 threads = 8 waves: wave = (cg = wv&3) x (rh = wv>>2).
// Conv (proven R0 mapping): wave owns o-tile cg for kbanks {2rh,2rh+1}.
// (i) vectorized staging -- thread = (sample, ch-quad, pix-quarter):
//     4x coalesced floatx4 reads + 4x half4 LDS writes (was 16x scalar
//     b16), pooled mean via shfl_xor tree;
// (ii) balanced epilogue -- both rh halves write unweighted float2
//     partials into the 16-B bases slots, then ALL 8 waves split the
//     attn-combine + silu + bases (2 samples each).
// FIX vs R7: softmax runs on the FULL wave 0 (64 lanes -> 16 samples).
__global__ __launch_bounds__(512, 4) void fused_kernel(
    const float* __restrict__ x, const _Float16* __restrict__ W3,
    const _Float16* __restrict__ Wk3, const _Float16* __restrict__ Wf3,
    const float* __restrict__ bias, const float* __restrict__ fc1_b,
    const float* __restrict__ fc2_w, const float* __restrict__ fc2_b,
    float* __restrict__ out)
{
    // Overlay: phase A = Xs dbuf [0,41984) + Pl [41984,50432)
    //          phase B = Act (16*2312 fp16 = 73984 B), partials in slots
    __shared__ __align__(16) char smem[MS * 2312 * 2];
    __shared__ float hid_lds[MS * 68];
    __shared__ float attn_s[MS][4];

    _Float16* Xs  = (_Float16*)smem;
    _Float16* Pl  = (_Float16*)(smem + 2 * XBUF * 2);
    _Float16* Act = (_Float16*)smem;

    const int tid = threadIdx.x;
    const int wv = tid >> 6, lane = tid & 63;
    const int nl = lane & 15, q = lane >> 4;
    const int cg = wv & 3, rh = wv >> 2;
    const int b0i = blockIdx.x * MS;

    // conv A-fragment base (halves): sample + pixel + k
    const int posr = nl & 3;
    const int aLane = (nl >> 2) * 656 + ((posr >> 1) * 4 + (posr & 1)) * 40 + q * 8;
    // B-fragment lane offsets for this wave's two kbanks (2rh, 2rh+1)
    const int lbW0 = (((rh * 2 + 0) * 4 + cg) * 16 + nl) * 32 + q * 8;
    const int lbW1 = (((rh * 2 + 1) * 4 + cg) * 16 + nl) * 32 + q * 8;

    // staging: thread = (sample s_, channel-quad qd, pixel-quarter pq)
    const int s_ = tid >> 5, w32 = tid & 31;
    const int qd = w32 & 7, pq = w32 >> 3;
    const float* xg = x + ((size_t)(b0i + s_) * 256 + qd * 4) * 16 + pq * 4;

    floatx4 acc[4][2];
    #pragma unroll
    for (int rt = 0; rt < 4; ++rt) {
        acc[rt][0] = floatx4{0.f, 0.f, 0.f, 0.f};
        acc[rt][1] = floatx4{0.f, 0.f, 0.f, 0.f};
    }

    // B prologue: taps 0 and 1 (2-deep pipeline, rolls over chunk bounds)
    half8 bA0 = *(const half8*)(W3 + lbW0);
    half8 bB0 = *(const half8*)(W3 + lbW1);
    half8 bA1 = *(const half8*)(W3 + 8192 + lbW0);
    half8 bB1 = *(const half8*)(W3 + 8192 + lbW1);

    // ---- staging helper (stage regs r0..r3 for chunk ch into buf bf) ----
    floatx4 r0, r1, r2, r3;
    #define STAGE_POOL(bf, ch)                                             \
    {                                                                      \
        _Float16* xd = &Xs[(bf) * XBUF + s_ * 656 + qd * 4];               \
        _Pragma("unroll")                                                  \
        for (int pl = 0; pl < 4; ++pl) {                                   \
            half4v w;                                                      \
            w[0] = (_Float16)r0[pl]; w[1] = (_Float16)r1[pl];              \
            w[2] = (_Float16)r2[pl]; w[3] = (_Float16)r3[pl];              \
            *(half4v*)&xd[(pq * 4 + pl) * 40] = w;                         \
        }                                                                  \
        float p0s = r0[0] + r0[1] + r0[2] + r0[3];                         \
        float p1s = r1[0] + r1[1] + r1[2] + r1[3];                         \
        float p2s = r2[0] + r2[1] + r2[2] + r2[3];                         \
        float p3s = r3[0] + r3[1] + r3[2] + r3[3];                         \
        p0s += __shfl_xor(p0s, 8);  p1s += __shfl_xor(p1s, 8);             \
        p2s += __shfl_xor(p2s, 8);  p3s += __shfl_xor(p3s, 8);             \
        p0s += __shfl_xor(p0s, 16); p1s += __shfl_xor(p1s, 16);            \
        p2s += __shfl_xor(p2s, 16); p3s += __shfl_xor(p3s, 16);            \
        if (pq == 0) {                                                     \
            half4v pw;                                                     \
            pw[0] = (_Float16)(p0s * 0.0625f);                             \
            pw[1] = (_Float16)(p1s * 0.0625f);                             \
            pw[2] = (_Float16)(p2s * 0.0625f);                             \
            pw[3] = (_Float16)(p3s * 0.0625f);                             \
            *(half4v*)&Pl[s_ * 264 + (ch) * 32 + qd * 4] = pw;             \
        }                                                                  \
    }

    // prologue: stage chunk 0 into buf 0, prefetch chunk 1
    r0 = *(const floatx4*)(xg);
    r1 = *(const floatx4*)(xg + 16);
    r2 = *(const floatx4*)(xg + 32);
    r3 = *(const floatx4*)(xg + 48);
    STAGE_POOL(0, 0)
    r0 = *(const floatx4*)(xg + 512);
    r1 = *(const floatx4*)(xg + 512 + 16);
    r2 = *(const floatx4*)(xg + 512 + 32);
    r3 = *(const floatx4*)(xg + 512 + 48);
    __syncthreads();

    #pragma unroll 1
    for (int cc = 0; cc < 8; ++cc) {
        const int cur = cc & 1;
        if (cc < 7) STAGE_POOL(cur ^ 1, cc + 1)
        if (cc < 6) {
            const float* xn = xg + (cc + 2) * 512;
            r0 = *(const floatx4*)(xn);
            r1 = *(const floatx4*)(xn + 16);
            r2 = *(const floatx4*)(xn + 32);
            r3 = *(const floatx4*)(xn + 48);
        }

        const _Float16* wst = W3 + (size_t)cc * 9 * 8192;
        const _Float16* xb = &Xs[cur * XBUF + aLane];

        // pixel index per tap: p0 = (ij/3)*4 + ij%3
        const int p0tab[9] = {0, 1, 2, 4, 5, 6, 8, 9, 10};

        #pragma unroll
        for (int ij = 0; ij < 9; ++ij) {
            // 2-deep rolling B prefetch (contiguous across chunk bounds)
            const _Float16* wnx = (cc * 9 + ij + 2 < 72)
                                ? (wst + (size_t)(ij + 2) * 8192)
                                : W3;          // dummy (valid) at the tail
            half8 bA2 = *(const half8*)(wnx + lbW0);
            half8 bB2 = *(const half8*)(wnx + lbW1);

            const int p0 = p0tab[ij];
            half8 aF[4];
            #pragma unroll
            for (int rt = 0; rt < 4; ++rt)
                aF[rt] = *(const half8*)&xb[rt * 2624 + p0 * 40];
            #pragma unroll
            for (int rt = 0; rt < 4; ++rt) {
                acc[rt][0] = __builtin_amdgcn_mfma_f32_16x16x32_f16(aF[rt], bA0, acc[rt][0], 0, 0, 0);
                acc[rt][1] = __builtin_amdgcn_mfma_f32_16x16x32_f16(aF[rt], bB0, acc[rt][1], 0, 0, 0);
            }
            bA0 = bA1; bB0 = bB1; bA1 = bA2; bB1 = bB2;
        }
        __syncthreads();
    }

    // ---- fc1 via MFMA (rh==0 waves, h-tile cg); 16 sample-rows valid ----
    if (rh == 0) {
        floatx4 a1 = floatx4{0.f, 0.f, 0.f, 0.f};
        const _Float16* wfb = Wf3 + ((cg * 16 + nl) * 32 + q * 8);
        const _Float16* pb = &Pl[nl * 264 + q * 8];
        #pragma unroll
        for (int st = 0; st < 8; ++st) {
            const half8 aF = *(const half8*)(pb + st * 32);
            const half8 bF = *(const half8*)(wfb + st * 2048);
            a1 = __builtin_amdgcn_mfma_f32_16x16x32_f16(aF, bF, a1, 0, 0, 0);
        }
        const int h = cg * 16 + nl;
        const float fb = fc1_b[h];
        #pragma unroll
        for (int reg = 0; reg < 4; ++reg)
            hid_lds[(q * 4 + reg) * 68 + h] = fmaxf(a1[reg] + fb, 0.f);
    }
    __syncthreads();   // Pl dead after this point

    // ---- fc2 + softmax (FULL wave 0: 16 s x 4 kb = 64 lanes) in parallel
    //      with unweighted partial writes (ALL waves) ----
    if (wv == 0) {
        const int s = lane >> 2, kb = lane & 3;
        float l = fc2_b[kb];
        #pragma unroll 8
        for (int h = 0; h < 64; ++h) l += hid_lds[s * 68 + h] * fc2_w[kb * 64 + h];
        float m = fmaxf(l, __shfl_xor(l, 1));
        m = fmaxf(m, __shfl_xor(m, 2));
        const float e = __expf((l - m) * (1.0f / 34.0f));
        float sm = e + __shfl_xor(e, 1);
        sm += __shfl_xor(sm, 2);
        attn_s[s][kb] = e / sm;
    }
    const int o = cg * 16 + nl;
    #pragma unroll
    for (int rt = 0; rt < 4; ++rt) {
        const int s = rt * 4 + q;
        #pragma unroll
        for (int e = 0; e < 4; ++e) {
            floatx2 pr; pr[0] = acc[rt][0][e]; pr[1] = acc[rt][1][e];
            float* fp = (float*)&Act[s * 2312 + 256 + ((o * 4 + e) * 8)];
            *(floatx2*)(fp + rh * 2) = pr;     // kbanks {2rh, 2rh+1}
        }
    }
    __syncthreads();   // attn + all 4 partials ready

    // ---- epilogue: ALL waves; wave wv handles samples {2wv, 2wv+1} ----
    {
        const int sl = lane >> 5, fl = lane & 31;
        const int s = wv * 2 + sl;
        const float a0 = attn_s[s][0], a1 = attn_s[s][1],
                    a2 = attn_s[s][2], a3 = attn_s[s][3];
        const int o0 = fl * 2, f0 = fl * 8;
        const float badd0 = a0 * bias[o0] + a1 * bias[64 + o0]
                          + a2 * bias[128 + o0] + a3 * bias[192 + o0];
        const float badd1 = a0 * bias[o0 + 1] + a1 * bias[64 + o0 + 1]
                          + a2 * bias[128 + o0 + 1] + a3 * bias[192 + o0 + 1];
        half8 sv;
        #pragma unroll
        for (int u = 0; u < 8; ++u) {
            float* fp = (float*)&Act[s * 2312 + 256 + (f0 + u) * 8];
            const floatx4 P = *(const floatx4*)fp;
            const float fv = a0 * P[0] + a1 * P[1] + a2 * P[2] + a3 * P[3]
                           + ((u < 4) ? badd0 : badd1);
            const float ex = __expf(-fv);
            sv[u] = (_Float16)(fv * __builtin_amdgcn_rcpf(1.f + ex));
            bases8c(fv, (_Float16*)fp);
        }
        *(half8*)&Act[s * 2312 + o0 * 4] = sv;   // silu for o0, o0+1
    }
    __syncthreads();

    // ---- KAN GEMM: split-K by rh, o-tile cg, 16 sample-rows ----
    {
        floatx4 a2 = floatx4{0.f, 0.f, 0.f, 0.f};
        const _Float16* wkb = Wk3 + ((size_t)(cg * 16 + nl) * 32 + q * 8);
        const _Float16* ab = &Act[nl * 2312 + q * 8];
        const int st0 = rh * 36;
        half8 kb0 = *(const half8*)(wkb + (size_t)st0 * 2048);
        half8 kb1 = *(const half8*)(wkb + (size_t)(st0 + 1) * 2048);
        #pragma unroll 4
        for (int i = 0; i < 36; ++i) {
            half8 kb2;
            if (i < 34) kb2 = *(const half8*)(wkb + (size_t)(st0 + i + 2) * 2048);
            const half8 aF = *(const half8*)(ab + (st0 + i) * 32);
            a2 = __builtin_amdgcn_mfma_f32_16x16x32_f16(aF, kb0, a2, 0, 0, 0);
            kb0 = kb1; kb1 = kb2;
        }
        if (rh == 1) *(floatx4*)&hid_lds[cg * 256 + lane * 4] = a2;
        __syncthreads();
        if (rh == 0) {
            const floatx4 p = *(const floatx4*)&hid_lds[cg * 256 + lane * 4];
            a2 = a2 + p;
            #pragma unroll
            for (int reg = 0; reg < 4; ++reg)
                out[(size_t)(b0i + q * 4 + reg) * 64 + cg * 16 + nl] = a2[reg];
        }
    }
}

extern "C" void kernel_launch(void* const* d_in, const int* in_sizes, int n_in,
                              void* d_out, int out_size, void* d_ws, size_t ws_size,
                              hipStream_t stream) {
    const float* x          = (const float*)d_in[0];
    const float* weight     = (const float*)d_in[1];
    const float* bias       = (const float*)d_in[2];
    const float* fc1_w      = (const float*)d_in[3];
    const float* fc1_b      = (const float*)d_in[4];
    const float* fc2_w      = (const float*)d_in[5];
    const float* fc2_b      = (const float*)d_in[6];
    const float* kan_base_w = (const float*)d_in[7];
    const float* kan_spline = (const float*)d_in[8];
    const float* kan_scaler = (const float*)d_in[9];
    float* out = (float*)d_out;

    // ws: W3 (72*8192 halves) | Wk3 (72*2048) | Wf3 (8*2048)
    _Float16* W3  = (_Float16*)d_ws;
    _Float16* Wk3 = W3 + (size_t)72 * 8192;
    _Float16* Wf3 = Wk3 + (size_t)72 * 2048;

    prep_kernel<<<336, 256, 0, stream>>>(weight, kan_base_w, kan_spline,
                                         kan_scaler, fc1_w, W3, Wk3, Wf3);
    fused_kernel<<<BT / MS, 512, 0, stream>>>(x, W3, Wk3, Wf3, bias, fc1_b,
                                              fc2_w, fc2_b, out);
}

// Round 9
// 245.614 us; speedup vs baseline: 1.2619x; 1.0088x over previous
//
#include <hip/hip_runtime.h>

#define BT   8192
#define MS   16               // samples per fused block
#define XBUF (MS * 656)       // halves per Xs buffer

typedef _Float16 half8  __attribute__((ext_vector_type(8)));
typedef _Float16 half4v __attribute__((ext_vector_type(4)));
typedef float    floatx2  __attribute__((ext_vector_type(2)));
typedef float    floatx4  __attribute__((ext_vector_type(4)));
typedef float    floatx16 __attribute__((ext_vector_type(16)));

// Act bases-slot XOR swizzle: slot(f) = 256 + (f ^ ((f>>3)&7))*8 halves.
// Bijective, keeps 16B alignment, spreads the f-stride-16B slots across
// bank groups (was: all lanes with f = fl*8+u in ONE group -> 32-way).
__device__ __forceinline__ int slotOff(int f) {
    return 256 + ((f ^ ((f >> 3) & 7)) << 3);
}

// ---------------- K0: all weight pre-transforms in one launch -------------
// blocks 0..255   : conv weight -> W3[step][256n][32c]
// blocks 256..327 : KAN weights -> Wk3
// blocks 328..335 : fc1 weights -> Wf3
__global__ __launch_bounds__(256) void prep_kernel(
    const float* __restrict__ weight, const float* __restrict__ base_w,
    const float* __restrict__ spline_w, const float* __restrict__ scaler,
    const float* __restrict__ fc1_w,
    _Float16* __restrict__ W3, _Float16* __restrict__ Wk3,
    _Float16* __restrict__ Wf3)
{
    const int bb = blockIdx.x;
    const int tid = threadIdx.x;
    if (bb < 256) {
        const int n = bb;              // 0..255  (= kbank*64 + o)
        const int c = tid;             // 0..255
        const float* src = weight + ((size_t)n * 256 + c) * 9;
        const int cc = c >> 5, ci = c & 31;
        #pragma unroll
        for (int ij = 0; ij < 9; ++ij) {
            W3[((size_t)(cc * 9 + ij) * 256 + n) * 32 + ci] = (_Float16)src[ij];
        }
    } else if (bb < 328) {
        const int st = bb - 256;       // 0..71
        #pragma unroll
        for (int u = 0; u < 8; ++u) {
            const int idx = u * 256 + tid;       // n*32 + kk
            const int n = idx >> 5, kk = idx & 31;
            const int k = st * 32 + kk;
            float v;
            if (k < 256) {
                v = base_w[n * 256 + k];
            } else {
                const int r = k - 256;
                const int i = r >> 3, g = r & 7;
                v = spline_w[((size_t)n * 256 + i) * 8 + g] * scaler[n * 256 + i];
            }
            Wk3[(size_t)st * 2048 + idx] = (_Float16)v;
        }
    } else {
        const int st2 = bb - 328;      // 0..7
        #pragma unroll
        for (int u = 0; u < 8; ++u) {
            const int idx = u * 256 + tid;
            const int n = idx >> 5, kk = idx & 31;
            Wf3[(size_t)st2 * 2048 + idx] = (_Float16)fc1_w[n * 256 + st2 * 32 + kk];
        }
    }
}

// Uniform cubic B-spline, closed form: only 4 of 8 bases nonzero.
// grid g[t] = (t-3)*0.4 - 1  ->  interval idx = floor((x+2.2)/0.4)
__device__ __forceinline__ void bases8c(float xv, _Float16* dst) {
    const float t = (xv + 2.2f) * 2.5f;
    const float ft = floorf(t);
    const int idx = (int)ft;
    const float u = t - ft, v = 1.f - u;
    const float u2 = u * u, v2 = v * v;
    const float c3 = u2 * u * (1.f / 6.f);                    // B_idx
    const float c2 = (1.f / 6.f) + 0.5f * (u + u2 - u2 * u);  // B_{idx-1}
    const float c1 = (1.f / 6.f) + 0.5f * (v + v2 - v2 * v);  // B_{idx-2}
    const float c0 = v2 * v * (1.f / 6.f);                    // B_{idx-3}
    half8 hb;
    #pragma unroll
    for (int tt = 0; tt < 8; ++tt) {
        const int d = idx - tt;
        float b = 0.f;
        b = (d == 0) ? c3 : b;
        b = (d == 1) ? c2 : b;
        b = (d == 2) ? c1 : b;
        b = (d == 3) ? c0 : b;
        hb[tt] = (_Float16)b;
    }
    *(half8*)dst = hb;
}

// ---------------- Fused: attn + dyn-conv (MFMA) + KAN (MFMA) -> out -------
// 512 threads = 8 waves: wave = (cg = wv&3) x (rh = wv>>2).
// Conv (proven R0 mapping): wave owns o-tile cg for kbanks {2rh,2rh+1}.
// Staging: R0 scalar form (proven). Epilogue: balanced (all 8 waves),
// partials exchanged as unweighted float2 per kbank-pair in the
// XOR-SWIZZLED bases slots; KAN reads use the matching swizzle.
__global__ __launch_bounds__(512, 4) void fused_kernel(
    const float* __restrict__ x, const _Float16* __restrict__ W3,
    const _Float16* __restrict__ Wk3, const _Float16* __restrict__ Wf3,
    const float* __restrict__ bias, const float* __restrict__ fc1_b,
    const float* __restrict__ fc2_w, const float* __restrict__ fc2_b,
    float* __restrict__ out)
{
    // Overlay: phase A = Xs dbuf [0,41984) + Pl [41984,50432)
    //          phase B = Act (16*2312 fp16 = 73984 B), partials in slots
    __shared__ __align__(16) char smem[MS * 2312 * 2];
    __shared__ float hid_lds[MS * 68];
    __shared__ float attn_s[MS][4];

    _Float16* Xs  = (_Float16*)smem;
    _Float16* Pl  = (_Float16*)(smem + 2 * XBUF * 2);
    _Float16* Act = (_Float16*)smem;

    const int tid = threadIdx.x;
    const int wv = tid >> 6, lane = tid & 63;
    const int nl = lane & 15, q = lane >> 4;
    const int cg = wv & 3, rh = wv >> 2;
    const int b0i = blockIdx.x * MS;

    // conv A-fragment base (halves): sample + pixel + k
    const int posr = nl & 3;
    const int aLane = (nl >> 2) * 656 + ((posr >> 1) * 4 + (posr & 1)) * 40 + q * 8;
    // B-fragment lane offsets for this wave's two kbanks (2rh, 2rh+1)
    const int lbW0 = (((rh * 2 + 0) * 4 + cg) * 16 + nl) * 32 + q * 8;
    const int lbW1 = (((rh * 2 + 1) * 4 + cg) * 16 + nl) * 32 + q * 8;

    // x staging (R0 scalar form): thread -> (sample s_, channel cch)
    const int s_ = tid >> 5, cch = tid & 31;
    const float* xg = x + ((size_t)(b0i + s_) * 256 + cch) * 16;

    floatx4 acc[4][2];
    #pragma unroll
    for (int rt = 0; rt < 4; ++rt) {
        acc[rt][0] = floatx4{0.f, 0.f, 0.f, 0.f};
        acc[rt][1] = floatx4{0.f, 0.f, 0.f, 0.f};
    }

    // B prologue: taps 0 and 1 (2-deep pipeline, rolls over chunk bounds)
    half8 bA0 = *(const half8*)(W3 + lbW0);
    half8 bB0 = *(const half8*)(W3 + lbW1);
    half8 bA1 = *(const half8*)(W3 + 8192 + lbW0);
    half8 bB1 = *(const half8*)(W3 + 8192 + lbW1);

    // prologue: stage chunk 0 into buf 0, prefetch chunk 1
    floatx16 r = *(const floatx16*)xg;
    {
        _Float16* xd = &Xs[s_ * 656 + cch];
        #pragma unroll
        for (int p = 0; p < 16; ++p) xd[p * 40] = (_Float16)r[p];
        float sm = 0.f;
        #pragma unroll
        for (int p = 0; p < 16; ++p) sm += r[p];
        Pl[s_ * 264 + cch] = (_Float16)(sm * (1.0f / 16.0f));
    }
    r = *(const floatx16*)(xg + 512);
    __syncthreads();

    #pragma unroll 1
    for (int cc = 0; cc < 8; ++cc) {
        const int cur = cc & 1;
        if (cc < 7) {      // stage chunk cc+1 into other buffer
            _Float16* xd = &Xs[(cur ^ 1) * XBUF + s_ * 656 + cch];
            #pragma unroll
            for (int p = 0; p < 16; ++p) xd[p * 40] = (_Float16)r[p];
            float sm = 0.f;
            #pragma unroll
            for (int p = 0; p < 16; ++p) sm += r[p];
            Pl[s_ * 264 + (cc + 1) * 32 + cch] = (_Float16)(sm * (1.0f / 16.0f));
        }
        if (cc < 6) r = *(const floatx16*)(xg + (cc + 2) * 512);

        const _Float16* wst = W3 + (size_t)cc * 9 * 8192;
        const _Float16* xb = &Xs[cur * XBUF + aLane];

        // pixel index per tap: p0 = (ij/3)*4 + ij%3
        const int p0tab[9] = {0, 1, 2, 4, 5, 6, 8, 9, 10};

        #pragma unroll
        for (int ij = 0; ij < 9; ++ij) {
            // 2-deep rolling B prefetch (contiguous across chunk bounds)
            const _Float16* wnx = (cc * 9 + ij + 2 < 72)
                                ? (wst + (size_t)(ij + 2) * 8192)
                                : W3;          // dummy (valid) at the tail
            half8 bA2 = *(const half8*)(wnx + lbW0);
            half8 bB2 = *(const half8*)(wnx + lbW1);

            const int p0 = p0tab[ij];
            half8 aF[4];
            #pragma unroll
            for (int rt = 0; rt < 4; ++rt)
                aF[rt] = *(const half8*)&xb[rt * 2624 + p0 * 40];
            #pragma unroll
            for (int rt = 0; rt < 4; ++rt) {
                acc[rt][0] = __builtin_amdgcn_mfma_f32_16x16x32_f16(aF[rt], bA0, acc[rt][0], 0, 0, 0);
                acc[rt][1] = __builtin_amdgcn_mfma_f32_16x16x32_f16(aF[rt], bB0, acc[rt][1], 0, 0, 0);
            }
            bA0 = bA1; bB0 = bB1; bA1 = bA2; bB1 = bB2;
        }
        __syncthreads();
    }

    // ---- fc1 via MFMA (rh==0 waves, h-tile cg); 16 sample-rows valid ----
    if (rh == 0) {
        floatx4 a1 = floatx4{0.f, 0.f, 0.f, 0.f};
        const _Float16* wfb = Wf3 + ((cg * 16 + nl) * 32 + q * 8);
        const _Float16* pb = &Pl[nl * 264 + q * 8];
        #pragma unroll
        for (int st = 0; st < 8; ++st) {
            const half8 aF = *(const half8*)(pb + st * 32);
            const half8 bF = *(const half8*)(wfb + st * 2048);
            a1 = __builtin_amdgcn_mfma_f32_16x16x32_f16(aF, bF, a1, 0, 0, 0);
        }
        const int h = cg * 16 + nl;
        const float fb = fc1_b[h];
        #pragma unroll
        for (int reg = 0; reg < 4; ++reg)
            hid_lds[(q * 4 + reg) * 68 + h] = fmaxf(a1[reg] + fb, 0.f);
    }
    __syncthreads();   // Pl dead after this point

    // ---- fc2 + softmax (FULL wave 0: 16 s x 4 kb) in parallel with
    //      unweighted partial writes (ALL waves, swizzled slots) ----
    if (wv == 0) {
        const int s = lane >> 2, kb = lane & 3;
        float l = fc2_b[kb];
        #pragma unroll 8
        for (int h = 0; h < 64; ++h) l += hid_lds[s * 68 + h] * fc2_w[kb * 64 + h];
        float m = fmaxf(l, __shfl_xor(l, 1));
        m = fmaxf(m, __shfl_xor(m, 2));
        const float e = __expf((l - m) * (1.0f / 34.0f));
        float sm = e + __shfl_xor(e, 1);
        sm += __shfl_xor(sm, 2);
        attn_s[s][kb] = e / sm;
    }
    const int o = cg * 16 + nl;
    #pragma unroll
    for (int rt = 0; rt < 4; ++rt) {
        const int s = rt * 4 + q;
        #pragma unroll
        for (int e = 0; e < 4; ++e) {
            floatx2 pr; pr[0] = acc[rt][0][e]; pr[1] = acc[rt][1][e];
            float* fp = (float*)&Act[s * 2312 + slotOff(o * 4 + e)];
            *(floatx2*)(fp + rh * 2) = pr;     // kbanks {2rh, 2rh+1}
        }
    }
    __syncthreads();   // attn + all 4 partials ready

    // ---- epilogue: ALL waves; wave wv handles samples {2wv, 2wv+1} ----
    {
        const int sl = lane >> 5, fl = lane & 31;
        const int s = wv * 2 + sl;
        const float a0 = attn_s[s][0], a1 = attn_s[s][1],
                    a2 = attn_s[s][2], a3 = attn_s[s][3];
        const int o0 = fl * 2, f0 = fl * 8;
        const float badd0 = a0 * bias[o0] + a1 * bias[64 + o0]
                          + a2 * bias[128 + o0] + a3 * bias[192 + o0];
        const float badd1 = a0 * bias[o0 + 1] + a1 * bias[64 + o0 + 1]
                          + a2 * bias[128 + o0 + 1] + a3 * bias[192 + o0 + 1];
        half8 sv;
        #pragma unroll
        for (int u = 0; u < 8; ++u) {
            float* fp = (float*)&Act[s * 2312 + slotOff(f0 + u)];
            const floatx4 P = *(const floatx4*)fp;
            const float fv = a0 * P[0] + a1 * P[1] + a2 * P[2] + a3 * P[3]
                           + ((u < 4) ? badd0 : badd1);
            const float ex = __expf(-fv);
            sv[u] = (_Float16)(fv * __builtin_amdgcn_rcpf(1.f + ex));
            bases8c(fv, (_Float16*)fp);
        }
        *(half8*)&Act[s * 2312 + o0 * 4] = sv;   // silu for o0, o0+1
    }
    __syncthreads();

    // ---- KAN GEMM: split-K by rh, o-tile cg, 16 sample-rows ----
    // A-read address: silu region (st<8) linear; bases region swizzled
    // with the lane-uniform XOR ((st-8)>>1)&7 (matches slotOff writer).
    {
        floatx4 a2 = floatx4{0.f, 0.f, 0.f, 0.f};
        const _Float16* wkb = Wk3 + ((size_t)(cg * 16 + nl) * 32 + q * 8);
        const _Float16* abr = &Act[nl * 2312];
        const int st0 = rh * 36;
        half8 kb0 = *(const half8*)(wkb + (size_t)st0 * 2048);
        half8 kb1 = *(const half8*)(wkb + (size_t)(st0 + 1) * 2048);
        #pragma unroll 4
        for (int i = 0; i < 36; ++i) {
            const int st = st0 + i;
            half8 kb2;
            if (i < 34) kb2 = *(const half8*)(wkb + (size_t)(st + 2) * 2048);
            const _Float16* ap;
            if (st < 8) {
                ap = abr + st * 32 + q * 8;
            } else {
                const int f  = st * 4 + q - 32;
                const int fx = f ^ (((st - 8) >> 1) & 7);
                ap = abr + 256 + (fx << 3);
            }
            const half8 aF = *(const half8*)ap;
            a2 = __builtin_amdgcn_mfma_f32_16x16x32_f16(aF, kb0, a2, 0, 0, 0);
            kb0 = kb1; kb1 = kb2;
        }
        if (rh == 1) *(floatx4*)&hid_lds[cg * 256 + lane * 4] = a2;
        __syncthreads();
        if (rh == 0) {
            const floatx4 p = *(const floatx4*)&hid_lds[cg * 256 + lane * 4];
            a2 = a2 + p;
            #pragma unroll
            for (int reg = 0; reg < 4; ++reg)
                out[(size_t)(b0i + q * 4 + reg) * 64 + cg * 16 + nl] = a2[reg];
        }
    }
}

extern "C" void kernel_launch(void* const* d_in, const int* in_sizes, int n_in,
                              void* d_out, int out_size, void* d_ws, size_t ws_size,
                              hipStream_t stream) {
    const float* x          = (const float*)d_in[0];
    const float* weight     = (const float*)d_in[1];
    const float* bias       = (const float*)d_in[2];
    const float* fc1_w      = (const float*)d_in[3];
    const float* fc1_b      = (const float*)d_in[4];
    const float* fc2_w      = (const float*)d_in[5];
    const float* fc2_b      = (const float*)d_in[6];
    const float* kan_base_w = (const float*)d_in[7];
    const float* kan_spline = (const float*)d_in[8];
    const float* kan_scaler = (const float*)d_in[9];
    float* out = (float*)d_out;

    // ws: W3 (72*8192 halves) | Wk3 (72*2048) | Wf3 (8*2048)
    _Float16* W3  = (_Float16*)d_ws;
    _Float16* Wk3 = W3 + (size_t)72 * 8192;
    _Float16* Wf3 = Wk3 + (size_t)72 * 2048;

    prep_kernel<<<336, 256, 0, stream>>>(weight, kan_base_w, kan_spline,
                                         kan_scaler, fc1_w, W3, Wk3, Wf3);
    fused_kernel<<<BT / MS, 512, 0, stream>>>(x, W3, Wk3, Wf3, bias, fc1_b,
                                              fc2_w, fc2_b, out);
}